// Round 4
// baseline (38427.805 us; speedup 1.0000x reference)
//
#include <hip/hip_runtime.h>
#include <hip/hip_bf16.h>
#include <stddef.h>
#include <math.h>

static constexpr int B = 64, P = 196, ED = 2048, AD = 512, DD = 512, E = 300, V = 1000, T = 96, TD = 95;
static constexpr int KX = E + ED;      // 2348
static constexpr int KTOT = KX + DD;   // 2860
static constexpr int KSPLIT = 8;
static constexpr int KPER = 368;       // 23 tiles of 16; 8*368 = 2944 >= 2860
static constexpr int NG = 4 * DD;      // 2048
static constexpr int NBLK = 256;       // persistent grid size

// d_out layout (all float32): predictions (B,TD,V), caps (B,T), decode_lengths (B),
// alphas (B,TD,P), sort_ind (B)
static constexpr size_t POFF   = 0;
static constexpr size_t CAPOFF = (size_t)B * TD * V;
static constexpr size_t DLOFF  = CAPOFF + (size_t)B * T;
static constexpr size_t AOFF   = DLOFF + B;
static constexpr size_t SOFF   = AOFF + (size_t)B * TD * P;

__device__ __forceinline__ float sigm(float x) { return 1.0f / (1.0f + expf(-x)); }

// ---------------------------------------------------------------------------
// Device-scope grid barrier (sense via monotonically increasing generation).
// All NBLK blocks must be co-resident (they are: tiny LDS/VGPR footprint).
// ---------------------------------------------------------------------------
__device__ __forceinline__ void gbar(int* cnt, int* gen) {
    __syncthreads();
    if (threadIdx.x == 0) {
        __threadfence();
        int g = __hip_atomic_load(gen, __ATOMIC_RELAXED, __HIP_MEMORY_SCOPE_AGENT);
        int a = __hip_atomic_fetch_add(cnt, 1, __ATOMIC_ACQ_REL, __HIP_MEMORY_SCOPE_AGENT);
        if (a == NBLK - 1) {
            __hip_atomic_store(cnt, 0, __ATOMIC_RELAXED, __HIP_MEMORY_SCOPE_AGENT);
            __hip_atomic_store(gen, g + 1, __ATOMIC_RELEASE, __HIP_MEMORY_SCOPE_AGENT);
        } else {
            while (__hip_atomic_load(gen, __ATOMIC_ACQUIRE, __HIP_MEMORY_SCOPE_AGENT) <= g)
                __builtin_amdgcn_s_sleep(2);
        }
        __threadfence();
    }
    __syncthreads();
}

// ---------------------------------------------------------------------------
// K0: stable descending sort by length + gather caps + write int-ish outputs
// ---------------------------------------------------------------------------
__global__ __launch_bounds__(64) void k_sort(const int* __restrict__ lens,
                                             const int* __restrict__ caps_in,
                                             int* __restrict__ sidx,
                                             int* __restrict__ dlen,
                                             int* __restrict__ caps_s,
                                             float* __restrict__ out) {
    __shared__ int sl[B];
    __shared__ int ss[B];
    int i = threadIdx.x;
    sl[i] = lens[i];
    __syncthreads();
    int li = sl[i];
    int r = 0;
    for (int j = 0; j < B; j++) {
        int lj = sl[j];
        r += (lj > li) || (lj == li && j < i);
    }
    ss[r] = i;
    sidx[r] = i;
    dlen[r] = li - 1;
    out[DLOFF + r] = (float)(li - 1);
    out[SOFF + r] = (float)i;
    __syncthreads();
    for (int idx = i; idx < B * T; idx += B) {
        int b = idx / T, tt = idx % T;
        int v = caps_in[ss[b] * T + tt];
        caps_s[idx] = v;
        out[CAPOFF + idx] = (float)v;
    }
}

// ---------------------------------------------------------------------------
// K1: mean over P of sorted encoder_out -> mean_eo (B, ED)
// ---------------------------------------------------------------------------
__global__ __launch_bounds__(256) void k_mean(const float* __restrict__ eo,
                                              const int* __restrict__ sidx,
                                              float* __restrict__ mean_eo) {
    int b = blockIdx.y;
    int d = blockIdx.x * 256 + threadIdx.x;
    const float* base = eo + ((size_t)sidx[b] * P) * ED + d;
    float s = 0.f;
    for (int p = 0; p < P; p++) s += base[(size_t)p * ED];
    mean_eo[(size_t)b * ED + d] = s * (1.0f / (float)P);
}

// ---------------------------------------------------------------------------
// K2: h0/c0 init; seeds the h-rows of xR (row-major x buffer [B][KTOT])
// ---------------------------------------------------------------------------
__global__ __launch_bounds__(256) void k_init(const float* __restrict__ mean_eo,
                                              const float* __restrict__ Wh, const float* __restrict__ bh,
                                              const float* __restrict__ Wc, const float* __restrict__ bc,
                                              float* __restrict__ h0, float* __restrict__ c0,
                                              float* __restrict__ xR) {
    int idx = blockIdx.x * 256 + threadIdx.x;  // B*DD
    int b = idx >> 9, j = idx & 511;
    const float* m = mean_eo + (size_t)b * ED;
    float ah = bh[j], ac = bc[j];
    for (int k = 0; k < ED; k++) {
        float mv = m[k];
        ah += mv * Wh[(size_t)k * DD + j];
        ac += mv * Wc[(size_t)k * DD + j];
    }
    h0[idx] = ah;
    c0[idx] = ac;
    xR[(size_t)b * KTOT + KX + j] = ah;
}

// ---------------------------------------------------------------------------
// K3: att1[m,n] = eo_sorted[m,:] @ W_enc_att[:,n] + b   (row-major, B*P x AD)
// ---------------------------------------------------------------------------
__global__ __launch_bounds__(256) void k_att1(const float* __restrict__ eo,
                                              const float* __restrict__ W,
                                              const float* __restrict__ bias,
                                              const int* __restrict__ sidx,
                                              float* __restrict__ att1) {
    int m0 = blockIdx.x * 64, n0 = blockIdx.y * 64;
    __shared__ float sA[16][68];
    __shared__ float sB[16][68];
    int tid = threadIdx.x;
    int tx = tid & 15, ty = tid >> 4;
    float acc[4][4] = {};

    int la_m = tid >> 2;
    int la_k = (tid & 3) * 4;
    int lb_k = tid >> 4;
    int lb_n = (tid & 15) * 4;

    int mA = m0 + la_m;
    int bA = mA / P, pA = mA % P;
    const float* arow = eo + ((size_t)sidx[bA] * P + pA) * ED;

    for (int k0 = 0; k0 < ED; k0 += 16) {
        float4 av = *(const float4*)(arow + k0 + la_k);
        sA[la_k + 0][la_m] = av.x;
        sA[la_k + 1][la_m] = av.y;
        sA[la_k + 2][la_m] = av.z;
        sA[la_k + 3][la_m] = av.w;
        float4 bv = *(const float4*)(W + (size_t)(k0 + lb_k) * AD + n0 + lb_n);
        *(float4*)&sB[lb_k][lb_n] = bv;
        __syncthreads();
#pragma unroll
        for (int kk = 0; kk < 16; kk++) {
            float4 a4 = *(const float4*)&sA[kk][ty * 4];
            float4 b4 = *(const float4*)&sB[kk][tx * 4];
            float av_[4] = {a4.x, a4.y, a4.z, a4.w};
            float bv_[4] = {b4.x, b4.y, b4.z, b4.w};
#pragma unroll
            for (int i = 0; i < 4; i++)
#pragma unroll
                for (int j = 0; j < 4; j++) acc[i][j] += av_[i] * bv_[j];
        }
        __syncthreads();
    }
#pragma unroll
    for (int i = 0; i < 4; i++) {
        int m = m0 + ty * 4 + i;
        int n = n0 + tx * 4;
        float4 o;
        o.x = acc[i][0] + bias[n + 0];
        o.y = acc[i][1] + bias[n + 1];
        o.z = acc[i][2] + bias[n + 2];
        o.w = acc[i][3] + bias[n + 3];
        *(float4*)(att1 + (size_t)m * AD + n) = o;
    }
}

// ---------------------------------------------------------------------------
// K5: convert sorted encoder_out to bf16 (optional, if ws_size permits)
// ---------------------------------------------------------------------------
__global__ __launch_bounds__(256) void k_eob(const float* __restrict__ eo,
                                             const int* __restrict__ sidx,
                                             __hip_bfloat16* __restrict__ eob) {
    int row = blockIdx.x;  // b*P + p
    int b = row / P, p = row - b * P;
    const float* src = eo + ((size_t)sidx[b] * P + p) * ED;
    __hip_bfloat16* dst = eob + (size_t)row * ED;
    for (int d = threadIdx.x; d < ED; d += 256) dst[d] = __float2bfloat16(src[d]);
}

// ---------------------------------------------------------------------------
// Persistent loop kernel: all 95 steps, 5 grid barriers per step.
// Grid = 256 blocks x 256 threads (co-resident: ~9KB LDS, 4 waves/block).
// ---------------------------------------------------------------------------
__global__ __launch_bounds__(256, 1) void k_loop(
    const float* __restrict__ eo, const __hip_bfloat16* __restrict__ eob,
    const int* __restrict__ sidx, const int* __restrict__ dlen,
    const int* __restrict__ caps_s, const float* __restrict__ emb,
    const float* __restrict__ Wda, const float* __restrict__ bda,
    const float* __restrict__ Wfb, const float* __restrict__ bfb,
    const float* __restrict__ wfull, const float* __restrict__ bfull,
    const float* __restrict__ Wih, const float* __restrict__ Whh,
    const float* __restrict__ bih, const float* __restrict__ bhh,
    const float* __restrict__ att1, const float* __restrict__ h0,
    float* __restrict__ hseq, float* __restrict__ cb0, float* __restrict__ cb1,
    float* __restrict__ att2g, float* __restrict__ fg, float* __restrict__ alpha,
    float* __restrict__ xR, float* __restrict__ part,
    float* __restrict__ out, int* __restrict__ bar) {
    __shared__ float smem[2176];  // 8.7 KB, aliased per phase
    int bid = blockIdx.x, tid = threadIdx.x;
    int* cnt = bar;
    int* gen = bar + 16;  // separate cache lines

    for (int t = 0; t < TD; t++) {
        const float* hprev = (t == 0) ? h0 : (hseq + (size_t)(t - 1) * B * DD);
        float* cc = (t & 1) ? cb1 : cb0;
        float* cn = (t & 1) ? cb0 : cb1;

        // ---------------- P1: att2 (32 blk), fg (128 blk), emb gather (5 blk)
        if (bid < 160) {
            bool is_att = (bid < 32);
            int n0 = is_att ? bid * 16 : (bid - 32) * 16;
            float* sH = smem;          // [16][68]
            float* sW = smem + 1088;   // [16][17]
            int tb = tid & 15, tn = tid >> 4;
            float acc[4] = {0.f, 0.f, 0.f, 0.f};
            int sb = tid >> 2, sq = tid & 3;
            int wk = tid >> 4, wn = tid & 15;
            for (int k0 = 0; k0 < DD; k0 += 16) {
                float4 hv = *(const float4*)(hprev + (size_t)sb * DD + k0 + sq * 4);
                sH[(sq * 4 + 0) * 68 + sb] = hv.x;
                sH[(sq * 4 + 1) * 68 + sb] = hv.y;
                sH[(sq * 4 + 2) * 68 + sb] = hv.z;
                sH[(sq * 4 + 3) * 68 + sb] = hv.w;
                float wv;
                if (is_att) wv = Wda[(size_t)(k0 + wk) * AD + n0 + wn];
                else        wv = Wfb[(size_t)(k0 + wk) * ED + n0 + wn];
                sW[wk * 17 + wn] = wv;
                __syncthreads();
#pragma unroll
                for (int kk = 0; kk < 16; kk++) {
                    float4 h4 = *(const float4*)&sH[kk * 68 + tb * 4];
                    float w = sW[kk * 17 + tn];
                    acc[0] += h4.x * w;
                    acc[1] += h4.y * w;
                    acc[2] += h4.z * w;
                    acc[3] += h4.w * w;
                }
                __syncthreads();
            }
            int n = n0 + tn;
            if (is_att) {
                float bv = bda[n];
#pragma unroll
                for (int i = 0; i < 4; i++)
                    att2g[(size_t)(tb * 4 + i) * AD + n] = acc[i] + bv;
            } else {
                float bv = bfb[n];
#pragma unroll
                for (int i = 0; i < 4; i++)
                    fg[(size_t)(tb * 4 + i) * ED + n] = sigm(acc[i] + bv);
            }
        } else if (bid < 165) {
            int k0 = (bid - 160) * 60;
            int r = tid & 63, bq = tid >> 6;
            if (r < 60) {
                for (int pass = 0; pass < 16; pass++) {
                    int b = pass * 4 + bq;
                    int cap = caps_s[b * T + t];
                    xR[(size_t)b * KTOT + k0 + r] = emb[(size_t)cap * E + k0 + r];
                }
            }
        }
        gbar(cnt, gen);

        // ---------------- P2: e = relu(att1+att2)·wf + bf, softmax -> alpha (64 blk)
        if (bid < B) {
            int b = bid;
            float* sa2 = smem;
            float* swf = smem + 512;
            float* se = smem + 1024;
            float* red = smem + 1232;
            sa2[tid] = att2g[(size_t)b * AD + tid];
            sa2[tid + 256] = att2g[(size_t)b * AD + tid + 256];
            swf[tid] = wfull[tid];
            swf[tid + 256] = wfull[tid + 256];
            __syncthreads();
            int wv = tid >> 6, lane = tid & 63;
            float bf0 = bfull[0];
            for (int p = wv; p < P; p += 4) {
                const float* row = att1 + ((size_t)b * P + p) * AD + lane * 8;
                float4 u0 = *(const float4*)row;
                float4 u1 = *(const float4*)(row + 4);
                float4 s0 = *(const float4*)&sa2[lane * 8];
                float4 s1 = *(const float4*)&sa2[lane * 8 + 4];
                float4 w0 = *(const float4*)&swf[lane * 8];
                float4 w1 = *(const float4*)&swf[lane * 8 + 4];
                float acc = fmaxf(u0.x + s0.x, 0.f) * w0.x + fmaxf(u0.y + s0.y, 0.f) * w0.y +
                            fmaxf(u0.z + s0.z, 0.f) * w0.z + fmaxf(u0.w + s0.w, 0.f) * w0.w +
                            fmaxf(u1.x + s1.x, 0.f) * w1.x + fmaxf(u1.y + s1.y, 0.f) * w1.y +
                            fmaxf(u1.z + s1.z, 0.f) * w1.z + fmaxf(u1.w + s1.w, 0.f) * w1.w;
#pragma unroll
                for (int m = 32; m >= 1; m >>= 1) acc += __shfl_xor(acc, m, 64);
                if (lane == 0) se[p] = acc + bf0;
            }
            __syncthreads();
            red[tid] = (tid < P) ? se[tid] : -1e30f;
            __syncthreads();
            for (int s = 128; s > 0; s >>= 1) {
                if (tid < s) red[tid] = fmaxf(red[tid], red[tid + s]);
                __syncthreads();
            }
            float mx = red[0];
            __syncthreads();
            float ex = (tid < P) ? expf(se[tid] - mx) : 0.f;
            red[tid] = ex;
            __syncthreads();
            for (int s = 128; s > 0; s >>= 1) {
                if (tid < s) red[tid] += red[tid + s];
                __syncthreads();
            }
            float inv = 1.0f / red[0];
            if (tid < P) {
                float a = ex * inv;
                alpha[(size_t)b * P + tid] = a;
                float m = (dlen[b] > t) ? 1.f : 0.f;
                out[AOFF + ((size_t)b * TD + t) * P + tid] = a * m;
            }
        }
        gbar(cnt, gen);

        // ---------------- P3: awe·fg -> xR rows [E, E+ED) (256 blk: b x 4 d-quarters)
        {
            int b = bid >> 2, dq = bid & 3;
            float* sal = smem;
            if (tid < P) sal[tid] = alpha[(size_t)b * P + tid];
            __syncthreads();
            int d = dq * 512 + tid * 2;
            float a0 = 0.f, a1 = 0.f;
            if (eob) {
                const __hip_bfloat16* base = eob + ((size_t)b * P) * ED + d;
                for (int p = 0; p < P; p++) {
                    __hip_bfloat162 v = *(const __hip_bfloat162*)(base + (size_t)p * ED);
                    float2 f = __bfloat1622float2(v);
                    float al = sal[p];
                    a0 += f.x * al;
                    a1 += f.y * al;
                }
            } else {
                const float* base = eo + ((size_t)sidx[b] * P) * ED + d;
                for (int p = 0; p < P; p++) {
                    float2 f = *(const float2*)(base + (size_t)p * ED);
                    float al = sal[p];
                    a0 += f.x * al;
                    a1 += f.y * al;
                }
            }
            float2 g2 = *(const float2*)&fg[(size_t)b * ED + d];
            float2 o;
            o.x = a0 * g2.x;
            o.y = a1 * g2.y;
            *(float2*)&xR[(size_t)b * KTOT + E + d] = o;
        }
        gbar(cnt, gen);

        // ---------------- P4: gates partial GEMM (256 blk = 8 ksplit x 32 ntiles(64))
        {
            int ks = bid >> 5, nt = bid & 31;
            int n0 = nt * 64;
            float* sX = smem;          // [16][68]
            float* sW = smem + 1088;   // [16][68]
            int tb = tid & 15, tn = tid >> 4;
            float acc[4][4] = {};
            int kbase = ks * KPER;
            int sb = tid >> 2, sq = tid & 3;
            int wk = tid >> 4, wn4 = (tid & 15) * 4;
            for (int tile = 0; tile < 23; tile++) {
                int k0 = kbase + tile * 16;
                {
                    int kg = k0 + sq * 4;
                    float4 xv;
                    if (kg + 3 < KTOT) xv = *(const float4*)(xR + (size_t)sb * KTOT + kg);
                    else {
                        xv.x = (kg + 0 < KTOT) ? xR[(size_t)sb * KTOT + kg + 0] : 0.f;
                        xv.y = (kg + 1 < KTOT) ? xR[(size_t)sb * KTOT + kg + 1] : 0.f;
                        xv.z = (kg + 2 < KTOT) ? xR[(size_t)sb * KTOT + kg + 2] : 0.f;
                        xv.w = (kg + 3 < KTOT) ? xR[(size_t)sb * KTOT + kg + 3] : 0.f;
                    }
                    sX[(sq * 4 + 0) * 68 + sb] = xv.x;
                    sX[(sq * 4 + 1) * 68 + sb] = xv.y;
                    sX[(sq * 4 + 2) * 68 + sb] = xv.z;
                    sX[(sq * 4 + 3) * 68 + sb] = xv.w;
                }
                {
                    int kg = k0 + wk;
                    float4 wv = make_float4(0.f, 0.f, 0.f, 0.f);
                    if (kg < KX) wv = *(const float4*)(Wih + (size_t)kg * NG + n0 + wn4);
                    else if (kg < KTOT) wv = *(const float4*)(Whh + (size_t)(kg - KX) * NG + n0 + wn4);
                    *(float4*)&sW[wk * 68 + wn4] = wv;
                }
                __syncthreads();
#pragma unroll
                for (int kk = 0; kk < 16; kk++) {
                    float4 xv = *(const float4*)&sX[kk * 68 + tb * 4];
                    float4 wv = *(const float4*)&sW[kk * 68 + tn * 4];
                    float xa[4] = {xv.x, xv.y, xv.z, xv.w};
                    float wa[4] = {wv.x, wv.y, wv.z, wv.w};
#pragma unroll
                    for (int i = 0; i < 4; i++)
#pragma unroll
                        for (int j = 0; j < 4; j++) acc[i][j] += xa[i] * wa[j];
                }
                __syncthreads();
            }
            float* pr = part + (size_t)ks * B * NG;
#pragma unroll
            for (int i = 0; i < 4; i++) {
                float4 o = make_float4(acc[i][0], acc[i][1], acc[i][2], acc[i][3]);
                *(float4*)&pr[(size_t)(tb * 4 + i) * NG + n0 + tn * 4] = o;
            }
        }
        gbar(cnt, gen);

        // ---------------- P5: reduce partials + LSTM cell (256 blk x 128 thr)
        if (tid < 128) {
            int idx = bid * 128 + tid;
            int b = idx >> 9, j = idx & 511;
            float gi = bih[j] + bhh[j];
            float gf = bih[DD + j] + bhh[DD + j];
            float gg = bih[2 * DD + j] + bhh[2 * DD + j];
            float go = bih[3 * DD + j] + bhh[3 * DD + j];
#pragma unroll
            for (int s = 0; s < KSPLIT; s++) {
                const float* pr = part + ((size_t)s * B + b) * NG;
                gi += pr[j];
                gf += pr[DD + j];
                gg += pr[2 * DD + j];
                go += pr[3 * DD + j];
            }
            float cold = cc[idx], hold = hprev[idx];
            float cnew = sigm(gf) * cold + sigm(gi) * tanhf(gg);
            float hnew = sigm(go) * tanhf(cnew);
            bool m = dlen[b] > t;
            float h2 = m ? hnew : hold;
            float c2 = m ? cnew : cold;
            hseq[(size_t)t * B * DD + idx] = h2;
            cn[idx] = c2;
            xR[(size_t)b * KTOT + KX + j] = h2;
        }
        gbar(cnt, gen);
    }
}

// ---------------------------------------------------------------------------
// K4: batched preds GEMM: out[b,t,v] = mask * (hseq[t,b,:]@Wfc + bfc)
// ---------------------------------------------------------------------------
__global__ __launch_bounds__(256) void k_predsall(const float* __restrict__ hseq,
                                                  const float* __restrict__ Wfc,
                                                  const float* __restrict__ bfc,
                                                  const int* __restrict__ dlen,
                                                  float* __restrict__ out) {
    int t = blockIdx.x;
    int n0 = blockIdx.y * 64;
    int tid = threadIdx.x;
    int tx = tid & 15, ty = tid >> 4;
    __shared__ float sA[16][68];
    __shared__ float sB[16][68];
    float acc[4][4] = {};
    const float* A = hseq + (size_t)t * B * DD;

    for (int k0 = 0; k0 < DD; k0 += 16) {
        {
            int b = tid >> 2, q = tid & 3;
            float4 hv = *(const float4*)(A + (size_t)b * DD + k0 + q * 4);
            sA[q * 4 + 0][b] = hv.x;
            sA[q * 4 + 1][b] = hv.y;
            sA[q * 4 + 2][b] = hv.z;
            sA[q * 4 + 3][b] = hv.w;
        }
        {
            int kk = tid >> 4, nn = (tid & 15) * 4;
            int c = n0 + nn;
            const float* wrow = Wfc + (size_t)(k0 + kk) * V;
            float4 wv;
            if (c + 3 < V) wv = *(const float4*)(wrow + c);
            else {
                wv.x = (c + 0 < V) ? wrow[c + 0] : 0.f;
                wv.y = (c + 1 < V) ? wrow[c + 1] : 0.f;
                wv.z = (c + 2 < V) ? wrow[c + 2] : 0.f;
                wv.w = (c + 3 < V) ? wrow[c + 3] : 0.f;
            }
            *(float4*)&sB[kk][nn] = wv;
        }
        __syncthreads();
#pragma unroll
        for (int kk = 0; kk < 16; kk++) {
            float4 a4 = *(const float4*)&sA[kk][ty * 4];
            float4 b4 = *(const float4*)&sB[kk][tx * 4];
            float av_[4] = {a4.x, a4.y, a4.z, a4.w};
            float bv_[4] = {b4.x, b4.y, b4.z, b4.w};
#pragma unroll
            for (int i = 0; i < 4; i++)
#pragma unroll
                for (int j = 0; j < 4; j++) acc[i][j] += av_[i] * bv_[j];
        }
        __syncthreads();
    }
#pragma unroll
    for (int i = 0; i < 4; i++) {
        int b = ty * 4 + i;
        bool m = dlen[b] > t;
#pragma unroll
        for (int j = 0; j < 4; j++) {
            int n = n0 + tx * 4 + j;
            if (n < V)
                out[POFF + ((size_t)b * TD + t) * V + n] = m ? (acc[i][j] + bfc[n]) : 0.f;
        }
    }
}

// ---------------------------------------------------------------------------
extern "C" void kernel_launch(void* const* d_in, const int* in_sizes, int n_in,
                              void* d_out, int out_size, void* d_ws, size_t ws_size,
                              hipStream_t stream) {
    const float* eo    = (const float*)d_in[0];
    const int*   caps  = (const int*)d_in[1];
    const int*   lens  = (const int*)d_in[2];
    const float* emb   = (const float*)d_in[3];
    const float* Wea   = (const float*)d_in[4];
    const float* bea   = (const float*)d_in[5];
    const float* Wda   = (const float*)d_in[6];
    const float* bda   = (const float*)d_in[7];
    const float* wfull = (const float*)d_in[8];
    const float* bfull = (const float*)d_in[9];
    const float* Wih_  = (const float*)d_in[10];
    const float* bih_  = (const float*)d_in[11];
    const float* Wic   = (const float*)d_in[12];
    const float* bic   = (const float*)d_in[13];
    const float* Wfb   = (const float*)d_in[14];
    const float* bfb   = (const float*)d_in[15];
    const float* Wih   = (const float*)d_in[16];
    const float* bih   = (const float*)d_in[17];
    const float* Whh   = (const float*)d_in[18];
    const float* bhh   = (const float*)d_in[19];
    const float* Wfc   = (const float*)d_in[20];
    const float* bfc   = (const float*)d_in[21];
    float* out = (float*)d_out;

    char* w0 = (char*)d_ws;
    char* w = w0;
    auto carve = [&](size_t bytes) -> void* {
        void* p = (void*)w;
        w += (bytes + 255) & ~(size_t)255;
        return p;
    };
    int* bar       = (int*)carve(256);
    int* sidx      = (int*)carve(B * 4);
    int* dlen      = (int*)carve(B * 4);
    int* caps_s    = (int*)carve((size_t)B * T * 4);
    float* mean_eo = (float*)carve((size_t)B * ED * 4);
    float* h0      = (float*)carve((size_t)B * DD * 4);
    float* cb0     = (float*)carve((size_t)B * DD * 4);
    float* cb1     = (float*)carve((size_t)B * DD * 4);
    float* att1    = (float*)carve((size_t)B * P * AD * 4);
    float* alphaW  = (float*)carve((size_t)B * P * 4);
    float* att2g   = (float*)carve((size_t)B * AD * 4);
    float* fg      = (float*)carve((size_t)B * ED * 4);
    float* xR      = (float*)carve((size_t)B * KTOT * 4);
    float* part    = (float*)carve((size_t)KSPLIT * B * NG * 4);
    float* hseq    = (float*)carve((size_t)TD * B * DD * 4);
    // optional bf16 copy of sorted eo (51.4 MB) if workspace allows
    size_t eob_bytes = (size_t)B * P * ED * 2;
    __hip_bfloat16* eob = nullptr;
    size_t used = (size_t)(w - w0);
    if (used + eob_bytes + 256 <= ws_size)
        eob = (__hip_bfloat16*)carve(eob_bytes);

    k_sort<<<1, 64, 0, stream>>>(lens, caps, sidx, dlen, caps_s, out);
    k_mean<<<dim3(ED / 256, B), 256, 0, stream>>>(eo, sidx, mean_eo);
    k_init<<<(B * DD) / 256, 256, 0, stream>>>(mean_eo, Wih_, bih_, Wic, bic, h0, cb0, xR);
    k_att1<<<dim3((B * P) / 64, AD / 64), 256, 0, stream>>>(eo, Wea, bea, sidx, att1);
    if (eob) k_eob<<<B * P, 256, 0, stream>>>(eo, sidx, eob);

    hipMemsetAsync(bar, 0, 256, stream);
    k_loop<<<NBLK, 256, 0, stream>>>(eo, eob, sidx, dlen, caps_s, emb,
                                     Wda, bda, Wfb, bfb, wfull, bfull,
                                     Wih, Whh, bih, bhh, att1, h0,
                                     hseq, cb0, cb1, att2g, fg, alphaW,
                                     xR, part, out, bar);
    k_predsall<<<dim3(TD, 16), 256, 0, stream>>>(hseq, Wfc, bfc, dlen, out);
}

// Round 5
// 24160.506 us; speedup vs baseline: 1.5905x; 1.5905x over previous
//
#include <hip/hip_runtime.h>
#include <hip/hip_bf16.h>
#include <stddef.h>
#include <math.h>

static constexpr int B = 64, P = 196, ED = 2048, AD = 512, DD = 512, E = 300, V = 1000, T = 96, TD = 95;
static constexpr int KX = E + ED;      // 2348
static constexpr int KTOT = KX + DD;   // 2860
static constexpr int KSPLIT = 15;      // P4 K-splits
static constexpr int KPER = 192;       // 12 tiles of 16; 15*192 = 2880 >= 2860
static constexpr int KPAD = KSPLIT * KPER;  // 2880 rows in xT
static constexpr int NT4 = 12;         // tiles per split
static constexpr int NG = 4 * DD;      // 2048
static constexpr int NBLK = 256;       // persistent grid
static constexpr int BD = B * DD;

// d_out layout (float32): predictions (B,TD,V), caps (B,T), decode_lengths (B),
// alphas (B,TD,P), sort_ind (B)
static constexpr size_t POFF   = 0;
static constexpr size_t CAPOFF = (size_t)B * TD * V;
static constexpr size_t DLOFF  = CAPOFF + (size_t)B * T;
static constexpr size_t AOFF   = DLOFF + B;
static constexpr size_t SOFF   = AOFF + (size_t)B * TD * P;

__device__ __forceinline__ float sigm(float x) { return 1.0f / (1.0f + expf(-x)); }

// ---- coherent (MALL / sc0 sc1) access helpers: relaxed agent-scope atomics ----
__device__ __forceinline__ float cload(const float* p) {
    return __hip_atomic_load(p, __ATOMIC_RELAXED, __HIP_MEMORY_SCOPE_AGENT);
}
__device__ __forceinline__ void cstore(float* p, float v) {
    __hip_atomic_store(p, v, __ATOMIC_RELAXED, __HIP_MEMORY_SCOPE_AGENT);
}
__device__ __forceinline__ float2 cload2(const float* p) {
    unsigned long long u = __hip_atomic_load((const unsigned long long*)p,
                                             __ATOMIC_RELAXED, __HIP_MEMORY_SCOPE_AGENT);
    union { unsigned long long u; float2 f; } c;
    c.u = u;
    return c.f;
}
__device__ __forceinline__ void cstore2(float* p, float2 v) {
    union { float2 f; unsigned long long u; } c;
    c.f = v;
    __hip_atomic_store((unsigned long long*)p, c.u, __ATOMIC_RELAXED, __HIP_MEMORY_SCOPE_AGENT);
}

// ---------------------------------------------------------------------------
// Cache-neutral grid barrier: NO acquire/release fences (those emit per-XCD
// L2 invalidate/writeback on gfx950 and destroy read-only cache residency).
// Visibility of cross-block data is via the sc0/sc1 write-through atomics
// above; s_waitcnt(0) drains them to the MALL before arrival.
// ---------------------------------------------------------------------------
__device__ __forceinline__ void gbar(int* cnt, int* gen) {
    asm volatile("" ::: "memory");
    __syncthreads();
    if (threadIdx.x == 0) {
        __builtin_amdgcn_s_waitcnt(0);  // my write-through stores are at the MALL
        int g = __hip_atomic_load(gen, __ATOMIC_RELAXED, __HIP_MEMORY_SCOPE_AGENT);
        int a = __hip_atomic_fetch_add(cnt, 1, __ATOMIC_RELAXED, __HIP_MEMORY_SCOPE_AGENT);
        if (a == NBLK - 1) {
            __hip_atomic_store(cnt, 0, __ATOMIC_RELAXED, __HIP_MEMORY_SCOPE_AGENT);
            __builtin_amdgcn_s_waitcnt(0);  // cnt reset lands before gen flips
            __hip_atomic_store(gen, g + 1, __ATOMIC_RELAXED, __HIP_MEMORY_SCOPE_AGENT);
        } else {
            while (__hip_atomic_load(gen, __ATOMIC_RELAXED, __HIP_MEMORY_SCOPE_AGENT) <= g)
                __builtin_amdgcn_s_sleep(4);
        }
    }
    __syncthreads();
    asm volatile("" ::: "memory");
}

// ---------------------------------------------------------------------------
// K0: stable descending sort by length + gather caps + int-ish outputs
// ---------------------------------------------------------------------------
__global__ __launch_bounds__(64) void k_sort(const int* __restrict__ lens,
                                             const int* __restrict__ caps_in,
                                             int* __restrict__ sidx,
                                             int* __restrict__ dlen,
                                             int* __restrict__ caps_s,
                                             float* __restrict__ out) {
    __shared__ int sl[B];
    __shared__ int ss[B];
    int i = threadIdx.x;
    sl[i] = lens[i];
    __syncthreads();
    int li = sl[i];
    int r = 0;
    for (int j = 0; j < B; j++) {
        int lj = sl[j];
        r += (lj > li) || (lj == li && j < i);
    }
    ss[r] = i;
    sidx[r] = i;
    dlen[r] = li - 1;
    out[DLOFF + r] = (float)(li - 1);
    out[SOFF + r] = (float)i;
    __syncthreads();
    for (int idx = i; idx < B * T; idx += B) {
        int b = idx / T, tt = idx % T;
        int v = caps_in[ss[b] * T + tt];
        caps_s[idx] = v;
        out[CAPOFF + idx] = (float)v;
    }
}

// ---------------------------------------------------------------------------
// K1: mean over P of sorted encoder_out -> mean_eo (B, ED)
// ---------------------------------------------------------------------------
__global__ __launch_bounds__(256) void k_mean(const float* __restrict__ eo,
                                              const int* __restrict__ sidx,
                                              float* __restrict__ mean_eo) {
    int b = blockIdx.y;
    int d = blockIdx.x * 256 + threadIdx.x;
    const float* base = eo + ((size_t)sidx[b] * P) * ED + d;
    float s = 0.f;
    for (int p = 0; p < P; p++) s += base[(size_t)p * ED];
    mean_eo[(size_t)b * ED + d] = s * (1.0f / (float)P);
}

// ---------------------------------------------------------------------------
// K2: h0/c0; h0 -> hseqR row 0 and xT h-rows
// ---------------------------------------------------------------------------
__global__ __launch_bounds__(256) void k_init(const float* __restrict__ mean_eo,
                                              const float* __restrict__ Wh, const float* __restrict__ bh,
                                              const float* __restrict__ Wc, const float* __restrict__ bc,
                                              float* __restrict__ hseqR, float* __restrict__ c0,
                                              float* __restrict__ xT) {
    int idx = blockIdx.x * 256 + threadIdx.x;  // B*DD
    int b = idx >> 9, j = idx & 511;
    const float* m = mean_eo + (size_t)b * ED;
    float ah = bh[j], ac = bc[j];
    for (int k = 0; k < ED; k++) {
        float mv = m[k];
        ah += mv * Wh[(size_t)k * DD + j];
        ac += mv * Wc[(size_t)k * DD + j];
    }
    hseqR[idx] = ah;  // row 0 = h0
    c0[idx] = ac;
    xT[(size_t)(KX + j) * B + b] = ah;
}

// ---------------------------------------------------------------------------
// K3: att1 = eo_sorted @ W_enc_att + b.  128x128 tile, 8x8/thread, BK=8 dbuf.
//     M = 12544 (98 tiles), N = 512 (4 tiles).
// ---------------------------------------------------------------------------
__global__ __launch_bounds__(256) void k_att1(const float* __restrict__ eo,
                                              const float* __restrict__ W,
                                              const float* __restrict__ bias,
                                              const int* __restrict__ sidx,
                                              float* __restrict__ att1) {
    __shared__ float sA[2][8][132];
    __shared__ float sB[2][8][132];
    int tid = threadIdx.x;
    int m0 = blockIdx.x * 128, n0 = blockIdx.y * 128;

    int ml = tid >> 1;            // 0..127
    int kq = (tid & 1) * 4;       // 0 or 4
    int mA = m0 + ml;
    int bA = mA / P, pA = mA % P;
    const float* arow = eo + ((size_t)sidx[bA] * P + pA) * ED;
    int kb = tid >> 5;            // 0..7
    int nb4 = (tid & 31) * 4;     // 0..124

    float acc[8][8] = {};
    int tm = tid >> 4, tn = tid & 15;

    // preload tile 0
    {
        float4 av = *(const float4*)(arow + kq);
        sA[0][kq + 0][ml] = av.x;
        sA[0][kq + 1][ml] = av.y;
        sA[0][kq + 2][ml] = av.z;
        sA[0][kq + 3][ml] = av.w;
        float4 bv = *(const float4*)(W + (size_t)kb * AD + n0 + nb4);
        *(float4*)&sB[0][kb][nb4] = bv;
    }
    const int NT = ED / 8;  // 256
    for (int tile = 0; tile < NT; tile++) {
        int cur = tile & 1, nxt = cur ^ 1;
        __syncthreads();
        float4 av, bv;
        if (tile + 1 < NT) {
            int k0 = (tile + 1) * 8;
            av = *(const float4*)(arow + k0 + kq);
            bv = *(const float4*)(W + (size_t)(k0 + kb) * AD + n0 + nb4);
        }
#pragma unroll
        for (int kk = 0; kk < 8; kk++) {
            float4 a0 = *(const float4*)&sA[cur][kk][tm * 8];
            float4 a1 = *(const float4*)&sA[cur][kk][tm * 8 + 4];
            float4 b0 = *(const float4*)&sB[cur][kk][tn * 8];
            float4 b1 = *(const float4*)&sB[cur][kk][tn * 8 + 4];
            float aa[8] = {a0.x, a0.y, a0.z, a0.w, a1.x, a1.y, a1.z, a1.w};
            float bb[8] = {b0.x, b0.y, b0.z, b0.w, b1.x, b1.y, b1.z, b1.w};
#pragma unroll
            for (int i = 0; i < 8; i++)
#pragma unroll
                for (int j = 0; j < 8; j++) acc[i][j] += aa[i] * bb[j];
        }
        if (tile + 1 < NT) {
            sA[nxt][kq + 0][ml] = av.x;
            sA[nxt][kq + 1][ml] = av.y;
            sA[nxt][kq + 2][ml] = av.z;
            sA[nxt][kq + 3][ml] = av.w;
            *(float4*)&sB[nxt][kb][nb4] = bv;
        }
    }
#pragma unroll
    for (int i = 0; i < 8; i++) {
        int m = m0 + tm * 8 + i;
        int n = n0 + tn * 8;
#pragma unroll
        for (int j = 0; j < 8; j += 4) {
            float4 o;
            o.x = acc[i][j + 0] + bias[n + j + 0];
            o.y = acc[i][j + 1] + bias[n + j + 1];
            o.z = acc[i][j + 2] + bias[n + j + 2];
            o.w = acc[i][j + 3] + bias[n + j + 3];
            *(float4*)(att1 + (size_t)m * AD + n + j) = o;
        }
    }
}

// ---------------------------------------------------------------------------
// K5: bf16 copy of sorted encoder_out (optional)
// ---------------------------------------------------------------------------
__global__ __launch_bounds__(256) void k_eob(const float* __restrict__ eo,
                                             const int* __restrict__ sidx,
                                             __hip_bfloat16* __restrict__ eob) {
    int row = blockIdx.x;
    int b = row / P, p = row - b * P;
    const float* src = eo + ((size_t)sidx[b] * P + p) * ED;
    __hip_bfloat16* dst = eob + (size_t)row * ED;
    for (int d = threadIdx.x; d < ED; d += 256) dst[d] = __float2bfloat16(src[d]);
}

// ---------------------------------------------------------------------------
// Persistent loop: 95 steps x 4 cache-neutral grid barriers.
// Cross-block data via cload/cstore (MALL-coherent); read-only data via
// normal cached loads (stays L2-resident across steps).
// ---------------------------------------------------------------------------
__global__ __launch_bounds__(256, 1) void k_loop(
    const float* __restrict__ eo, const __hip_bfloat16* __restrict__ eob,
    const int* __restrict__ sidx, const int* __restrict__ dlen,
    const int* __restrict__ caps_s, const float* __restrict__ emb,
    const float* __restrict__ Wda, const float* __restrict__ bda,
    const float* __restrict__ Wfb, const float* __restrict__ bfb,
    const float* __restrict__ wfull, const float* __restrict__ bfull,
    const float* __restrict__ Wih, const float* __restrict__ Whh,
    const float* __restrict__ bih, const float* __restrict__ bhh,
    const float* __restrict__ att1,
    float* __restrict__ hseqR, float* __restrict__ cb0, float* __restrict__ cb1,
    float* __restrict__ fg, float* __restrict__ alpha,
    float* __restrict__ xT, float* __restrict__ part,
    float* __restrict__ out, int* __restrict__ bar) {
    __shared__ float smem[6400];  // 25.6 KB, aliased per phase
    int bid = blockIdx.x, tid = threadIdx.x;
    int* cnt = bar;
    int* gen = bar + 32;

    for (int t = 0; t < TD; t++) {
        const float* hprev = hseqR + (size_t)t * BD;
        float* cc = (t & 1) ? cb1 : cb0;
        float* cn = (t & 1) ? cb0 : cb1;

        // ============ PhA: att2+softmax (blk 0-63) | fg GEMM (64-127) | emb (128-129)
        if (bid < 64) {
            int b = bid;
            float* sh  = smem;         // [512]
            float* sa2 = smem + 512;   // [512]
            float* swf = smem + 1024;  // [512]
            float* se  = smem + 1536;  // [224]
            float* red = smem + 1792;  // [256]
            sh[tid] = cload(hprev + (size_t)b * DD + tid);
            sh[tid + 256] = cload(hprev + (size_t)b * DD + tid + 256);
            swf[tid] = wfull[tid];
            swf[tid + 256] = wfull[tid + 256];
            __syncthreads();
            // att2[b][n], n = 2*tid, 2*tid+1 ; Wda L2-resident (same block every step)
            {
                int n2 = tid * 2;
                float a0 = 0.f, a1 = 0.f;
#pragma unroll 4
                for (int k = 0; k < DD; k++) {
                    float2 w2 = *(const float2*)(Wda + (size_t)k * AD + n2);
                    float hk = sh[k];
                    a0 += hk * w2.x;
                    a1 += hk * w2.y;
                }
                sa2[n2] = a0 + bda[n2];
                sa2[n2 + 1] = a1 + bda[n2 + 1];
            }
            __syncthreads();
            int wv = tid >> 6, lane = tid & 63;
            float bf0 = bfull[0];
            for (int p = wv; p < P; p += 4) {
                const float* row = att1 + ((size_t)b * P + p) * AD + lane * 8;
                float4 u0 = *(const float4*)row;
                float4 u1 = *(const float4*)(row + 4);
                float4 s0 = *(const float4*)&sa2[lane * 8];
                float4 s1 = *(const float4*)&sa2[lane * 8 + 4];
                float4 w0 = *(const float4*)&swf[lane * 8];
                float4 w1 = *(const float4*)&swf[lane * 8 + 4];
                float acc = fmaxf(u0.x + s0.x, 0.f) * w0.x + fmaxf(u0.y + s0.y, 0.f) * w0.y +
                            fmaxf(u0.z + s0.z, 0.f) * w0.z + fmaxf(u0.w + s0.w, 0.f) * w0.w +
                            fmaxf(u1.x + s1.x, 0.f) * w1.x + fmaxf(u1.y + s1.y, 0.f) * w1.y +
                            fmaxf(u1.z + s1.z, 0.f) * w1.z + fmaxf(u1.w + s1.w, 0.f) * w1.w;
#pragma unroll
                for (int m = 32; m >= 1; m >>= 1) acc += __shfl_xor(acc, m, 64);
                if (lane == 0) se[p] = acc + bf0;
            }
            __syncthreads();
            red[tid] = (tid < P) ? se[tid] : -1e30f;
            __syncthreads();
            for (int s = 128; s > 0; s >>= 1) {
                if (tid < s) red[tid] = fmaxf(red[tid], red[tid + s]);
                __syncthreads();
            }
            float mx = red[0];
            __syncthreads();
            float ex = (tid < P) ? expf(se[tid] - mx) : 0.f;
            red[tid] = ex;
            __syncthreads();
            for (int s = 128; s > 0; s >>= 1) {
                if (tid < s) red[tid] += red[tid + s];
                __syncthreads();
            }
            float inv = 1.0f / red[0];
            if (tid < P) {
                float a = ex * inv;
                cstore(alpha + (size_t)b * P + tid, a);
                float m = (dlen[b] > t) ? 1.f : 0.f;
                cstore(out + AOFF + ((size_t)b * TD + t) * P + tid, a * m);
            }
        } else if (bid < 128) {
            // fg n-tile GEMM: 32 cols per block; x = h (from xT K-major h rows)
            int n0 = (bid - 64) * 32;
            float* sX = smem;          // 2 x [16][68]
            float* sW = smem + 2176;   // 2 x [16][36]
            int tb = tid & 15, tn = tid >> 4;
            float acc[4][2] = {};
            int xk = tid >> 4, xc = (tid & 15) * 4;   // X staging
            int wk = tid >> 4, wn = (tid & 15) * 2;   // W staging
            // preload tile 0
            {
                const float* src = xT + (size_t)(KX + xk) * B + xc;
                float2 v0 = cload2(src), v1 = cload2(src + 2);
                sX[xk * 68 + xc + 0] = v0.x; sX[xk * 68 + xc + 1] = v0.y;
                sX[xk * 68 + xc + 2] = v1.x; sX[xk * 68 + xc + 3] = v1.y;
                float2 wv = *(const float2*)(Wfb + (size_t)wk * ED + n0 + wn);
                sW[wk * 36 + wn] = wv.x; sW[wk * 36 + wn + 1] = wv.y;
            }
            for (int tile = 0; tile < 32; tile++) {
                int cur = tile & 1, nxt = cur ^ 1;
                __syncthreads();
                float2 v0, v1, wv;
                if (tile + 1 < 32) {
                    int k0 = (tile + 1) * 16;
                    const float* src = xT + (size_t)(KX + k0 + xk) * B + xc;
                    v0 = cload2(src); v1 = cload2(src + 2);
                    wv = *(const float2*)(Wfb + (size_t)(k0 + wk) * ED + n0 + wn);
                }
                const float* bX = sX + cur * 1088;
                const float* bW = sW + cur * 576;
#pragma unroll
                for (int kk = 0; kk < 16; kk++) {
                    float4 xv = *(const float4*)&bX[kk * 68 + tb * 4];
                    float w0 = bW[kk * 36 + tn * 2];
                    float w1 = bW[kk * 36 + tn * 2 + 1];
                    acc[0][0] += xv.x * w0; acc[0][1] += xv.x * w1;
                    acc[1][0] += xv.y * w0; acc[1][1] += xv.y * w1;
                    acc[2][0] += xv.z * w0; acc[2][1] += xv.z * w1;
                    acc[3][0] += xv.w * w0; acc[3][1] += xv.w * w1;
                }
                if (tile + 1 < 32) {
                    float* nX = sX + nxt * 1088;
                    float* nW = sW + nxt * 576;
                    nX[xk * 68 + xc + 0] = v0.x; nX[xk * 68 + xc + 1] = v0.y;
                    nX[xk * 68 + xc + 2] = v1.x; nX[xk * 68 + xc + 3] = v1.y;
                    nW[wk * 36 + wn] = wv.x; nW[wk * 36 + wn + 1] = wv.y;
                }
            }
            int n = n0 + tn * 2;
            float b0 = bfb[n], b1 = bfb[n + 1];
#pragma unroll
            for (int i = 0; i < 4; i++) {
                int b = tb * 4 + i;
                float2 o;
                o.x = sigm(acc[i][0] + b0);
                o.y = sigm(acc[i][1] + b1);
                cstore2(fg + (size_t)b * ED + n, o);
            }
        } else if (bid < 130) {
            int g = bid - 128;  // 150 emb rows each
            for (int l = tid; l < 150 * 64; l += 256) {
                int r = l >> 6, b = l & 63;
                int k = g * 150 + r;
                int cap = caps_s[b * T + t];
                cstore(xT + (size_t)k * B + b, emb[(size_t)cap * E + k]);
            }
        }
        gbar(cnt, gen);

        // ============ P3: awe * fg -> xT rows [E, E+ED)  (256 blk = b x 4 dq)
        {
            int b = bid >> 2, dq = bid & 3;
            float* sal = smem;
            if (tid < P) sal[tid] = cload(alpha + (size_t)b * P + tid);
            __syncthreads();
            int d = dq * 512 + tid * 2;
            float a0 = 0.f, a1 = 0.f;
            if (eob) {
                const __hip_bfloat16* base = eob + ((size_t)b * P) * ED + d;
#pragma unroll 4
                for (int p = 0; p < P; p++) {
                    __hip_bfloat162 v = *(const __hip_bfloat162*)(base + (size_t)p * ED);
                    float2 f = __bfloat1622float2(v);
                    float al = sal[p];
                    a0 += f.x * al;
                    a1 += f.y * al;
                }
            } else {
                const float* base = eo + ((size_t)sidx[b] * P) * ED + d;
#pragma unroll 4
                for (int p = 0; p < P; p++) {
                    float2 f = *(const float2*)(base + (size_t)p * ED);
                    float al = sal[p];
                    a0 += f.x * al;
                    a1 += f.y * al;
                }
            }
            float2 g2 = cload2(fg + (size_t)b * ED + d);
            cstore(xT + (size_t)(E + d) * B + b, a0 * g2.x);
            cstore(xT + (size_t)(E + d + 1) * B + b, a1 * g2.y);
        }
        gbar(cnt, gen);

        // ============ P4: gates partial GEMM (240 blk = 15 ks x 16 nt(128))
        if (bid < KSPLIT * 16) {
            int ks = bid >> 4, nt = bid & 15;
            int n0 = nt * 128;
            int kbase = ks * KPER;
            float* sX = smem;          // 2 x [16][68]
            float* sW = smem + 2176;   // 2 x [16][132]
            int tb = tid & 15, tn = tid >> 4;
            float acc[4][8] = {};
            int xk = tid >> 4, xc = (tid & 15) * 4;
            int wk = tid >> 4, wn = (tid & 15) * 8;
            // preload tile 0
            {
                const float* src = xT + (size_t)(kbase + xk) * B + xc;
                float2 v0 = cload2(src), v1 = cload2(src + 2);
                sX[xk * 68 + xc + 0] = v0.x; sX[xk * 68 + xc + 1] = v0.y;
                sX[xk * 68 + xc + 2] = v1.x; sX[xk * 68 + xc + 3] = v1.y;
                int kg = kbase + wk;
                float4 w0 = make_float4(0.f, 0.f, 0.f, 0.f), w1 = w0;
                if (kg < KX) {
                    w0 = *(const float4*)(Wih + (size_t)kg * NG + n0 + wn);
                    w1 = *(const float4*)(Wih + (size_t)kg * NG + n0 + wn + 4);
                } else if (kg < KTOT) {
                    w0 = *(const float4*)(Whh + (size_t)(kg - KX) * NG + n0 + wn);
                    w1 = *(const float4*)(Whh + (size_t)(kg - KX) * NG + n0 + wn + 4);
                }
                *(float4*)&sW[wk * 132 + wn] = w0;
                *(float4*)&sW[wk * 132 + wn + 4] = w1;
            }
            for (int tile = 0; tile < NT4; tile++) {
                int cur = tile & 1, nxt = cur ^ 1;
                __syncthreads();
                float2 v0, v1;
                float4 w0, w1;
                if (tile + 1 < NT4) {
                    int k0 = kbase + (tile + 1) * 16;
                    const float* src = xT + (size_t)(k0 + xk) * B + xc;
                    v0 = cload2(src); v1 = cload2(src + 2);
                    int kg = k0 + wk;
                    w0 = make_float4(0.f, 0.f, 0.f, 0.f); w1 = w0;
                    if (kg < KX) {
                        w0 = *(const float4*)(Wih + (size_t)kg * NG + n0 + wn);
                        w1 = *(const float4*)(Wih + (size_t)kg * NG + n0 + wn + 4);
                    } else if (kg < KTOT) {
                        w0 = *(const float4*)(Whh + (size_t)(kg - KX) * NG + n0 + wn);
                        w1 = *(const float4*)(Whh + (size_t)(kg - KX) * NG + n0 + wn + 4);
                    }
                }
                const float* bX = sX + cur * 1088;
                const float* bW = sW + cur * 2112;
#pragma unroll
                for (int kk = 0; kk < 16; kk++) {
                    float4 xv = *(const float4*)&bX[kk * 68 + tb * 4];
                    float4 wa = *(const float4*)&bW[kk * 132 + tn * 8];
                    float4 wb = *(const float4*)&bW[kk * 132 + tn * 8 + 4];
                    float xa[4] = {xv.x, xv.y, xv.z, xv.w};
                    float wc[8] = {wa.x, wa.y, wa.z, wa.w, wb.x, wb.y, wb.z, wb.w};
#pragma unroll
                    for (int i = 0; i < 4; i++)
#pragma unroll
                        for (int j = 0; j < 8; j++) acc[i][j] += xa[i] * wc[j];
                }
                if (tile + 1 < NT4) {
                    float* nX = sX + nxt * 1088;
                    float* nW = sW + nxt * 2112;
                    nX[xk * 68 + xc + 0] = v0.x; nX[xk * 68 + xc + 1] = v0.y;
                    nX[xk * 68 + xc + 2] = v1.x; nX[xk * 68 + xc + 3] = v1.y;
                    *(float4*)&nW[wk * 132 + wn] = w0;
                    *(float4*)&nW[wk * 132 + wn + 4] = w1;
                }
            }
            float* pr = part + (size_t)ks * B * NG;
#pragma unroll
            for (int i = 0; i < 4; i++) {
                int b = tb * 4 + i;
                float* dst = pr + (size_t)b * NG + n0 + tn * 8;
#pragma unroll
                for (int j = 0; j < 8; j += 2)
                    cstore2(dst + j, make_float2(acc[i][j], acc[i][j + 1]));
            }
        }
        gbar(cnt, gen);

        // ============ P5: reduce partials + LSTM cell (256 blk x 128 thr)
        if (tid < 128) {
            int idx = bid * 128 + tid;
            int b = idx >> 9, j = idx & 511;
            float gi = bih[j] + bhh[j];
            float gf = bih[DD + j] + bhh[DD + j];
            float gg = bih[2 * DD + j] + bhh[2 * DD + j];
            float go = bih[3 * DD + j] + bhh[3 * DD + j];
#pragma unroll
            for (int s = 0; s < KSPLIT; s++) {
                const float* pr = part + ((size_t)s * B + b) * NG;
                gi += cload(pr + j);
                gf += cload(pr + DD + j);
                gg += cload(pr + 2 * DD + j);
                go += cload(pr + 3 * DD + j);
            }
            float cold = cc[idx];
            float hold = cload(hprev + idx);
            float cnew = sigm(gf) * cold + sigm(gi) * tanhf(gg);
            float hnew = sigm(go) * tanhf(cnew);
            bool m = dlen[b] > t;
            float h2 = m ? hnew : hold;
            float c2 = m ? cnew : cold;
            cn[idx] = c2;                                   // block-local, cached
            cstore(hseqR + (size_t)(t + 1) * BD + idx, h2); // coherent
            cstore(xT + (size_t)(KX + j) * B + b, h2);      // coherent
        }
        gbar(cnt, gen);
    }
}

// ---------------------------------------------------------------------------
// K4: batched preds GEMM: out[b,t,v] = mask * (hseqR[t+1,b,:]@Wfc + bfc)
// ---------------------------------------------------------------------------
__global__ __launch_bounds__(256) void k_predsall(const float* __restrict__ hseqR,
                                                  const float* __restrict__ Wfc,
                                                  const float* __restrict__ bfc,
                                                  const int* __restrict__ dlen,
                                                  float* __restrict__ out) {
    int t = blockIdx.x;
    int n0 = blockIdx.y * 64;
    int tid = threadIdx.x;
    int tx = tid & 15, ty = tid >> 4;
    __shared__ float sA[16][68];
    __shared__ float sB[16][68];
    float acc[4][4] = {};
    const float* A = hseqR + (size_t)(t + 1) * BD;

    for (int k0 = 0; k0 < DD; k0 += 16) {
        {
            int b = tid >> 2, q = tid & 3;
            float4 hv = *(const float4*)(A + (size_t)b * DD + k0 + q * 4);
            sA[q * 4 + 0][b] = hv.x;
            sA[q * 4 + 1][b] = hv.y;
            sA[q * 4 + 2][b] = hv.z;
            sA[q * 4 + 3][b] = hv.w;
        }
        {
            int kk = tid >> 4, nn = (tid & 15) * 4;
            int c = n0 + nn;
            const float* wrow = Wfc + (size_t)(k0 + kk) * V;
            float4 wv;
            if (c + 3 < V) wv = *(const float4*)(wrow + c);
            else {
                wv.x = (c + 0 < V) ? wrow[c + 0] : 0.f;
                wv.y = (c + 1 < V) ? wrow[c + 1] : 0.f;
                wv.z = (c + 2 < V) ? wrow[c + 2] : 0.f;
                wv.w = (c + 3 < V) ? wrow[c + 3] : 0.f;
            }
            *(float4*)&sB[kk][nn] = wv;
        }
        __syncthreads();
#pragma unroll
        for (int kk = 0; kk < 16; kk++) {
            float4 a4 = *(const float4*)&sA[kk][ty * 4];
            float4 b4 = *(const float4*)&sB[kk][tx * 4];
            float av_[4] = {a4.x, a4.y, a4.z, a4.w};
            float bv_[4] = {b4.x, b4.y, b4.z, b4.w};
#pragma unroll
            for (int i = 0; i < 4; i++)
#pragma unroll
                for (int j = 0; j < 4; j++) acc[i][j] += av_[i] * bv_[j];
        }
        __syncthreads();
    }
#pragma unroll
    for (int i = 0; i < 4; i++) {
        int b = ty * 4 + i;
        bool m = dlen[b] > t;
#pragma unroll
        for (int j = 0; j < 4; j++) {
            int n = n0 + tx * 4 + j;
            if (n < V)
                out[POFF + ((size_t)b * TD + t) * V + n] = m ? (acc[i][j] + bfc[n]) : 0.f;
        }
    }
}

// ---------------------------------------------------------------------------
extern "C" void kernel_launch(void* const* d_in, const int* in_sizes, int n_in,
                              void* d_out, int out_size, void* d_ws, size_t ws_size,
                              hipStream_t stream) {
    const float* eo    = (const float*)d_in[0];
    const int*   caps  = (const int*)d_in[1];
    const int*   lens  = (const int*)d_in[2];
    const float* emb   = (const float*)d_in[3];
    const float* Wea   = (const float*)d_in[4];
    const float* bea   = (const float*)d_in[5];
    const float* Wda   = (const float*)d_in[6];
    const float* bda   = (const float*)d_in[7];
    const float* wfull = (const float*)d_in[8];
    const float* bfull = (const float*)d_in[9];
    const float* Wih_  = (const float*)d_in[10];
    const float* bih_  = (const float*)d_in[11];
    const float* Wic   = (const float*)d_in[12];
    const float* bic   = (const float*)d_in[13];
    const float* Wfb   = (const float*)d_in[14];
    const float* bfb   = (const float*)d_in[15];
    const float* Wih   = (const float*)d_in[16];
    const float* bih   = (const float*)d_in[17];
    const float* Whh   = (const float*)d_in[18];
    const float* bhh   = (const float*)d_in[19];
    const float* Wfc   = (const float*)d_in[20];
    const float* bfc   = (const float*)d_in[21];
    float* out = (float*)d_out;

    char* w0 = (char*)d_ws;
    char* w = w0;
    auto carve = [&](size_t bytes) -> void* {
        void* p = (void*)w;
        w += (bytes + 255) & ~(size_t)255;
        return p;
    };
    int* bar       = (int*)carve(256);
    int* sidx      = (int*)carve(B * 4);
    int* dlen      = (int*)carve(B * 4);
    int* caps_s    = (int*)carve((size_t)B * T * 4);
    float* mean_eo = (float*)carve((size_t)B * ED * 4);
    float* cb0     = (float*)carve((size_t)BD * 4);
    float* cb1     = (float*)carve((size_t)BD * 4);
    float* att1    = (float*)carve((size_t)B * P * AD * 4);
    float* alphaW  = (float*)carve((size_t)B * P * 4);
    float* fg      = (float*)carve((size_t)B * ED * 4);
    float* xT      = (float*)carve((size_t)KPAD * B * 4);
    float* part    = (float*)carve((size_t)KSPLIT * B * NG * 4);
    float* hseqR   = (float*)carve((size_t)(TD + 1) * BD * 4);
    size_t eob_bytes = (size_t)B * P * ED * 2;
    __hip_bfloat16* eob = nullptr;
    if ((size_t)(w - w0) + eob_bytes + 256 <= ws_size)
        eob = (__hip_bfloat16*)carve(eob_bytes);

    k_sort<<<1, 64, 0, stream>>>(lens, caps, sidx, dlen, caps_s, out);
    k_mean<<<dim3(ED / 256, B), 256, 0, stream>>>(eo, sidx, mean_eo);
    k_init<<<BD / 256, 256, 0, stream>>>(mean_eo, Wih_, bih_, Wic, bic, hseqR, cb0, xT);
    k_att1<<<dim3(B * P / 128, AD / 128), 256, 0, stream>>>(eo, Wea, bea, sidx, att1);
    if (eob) k_eob<<<B * P, 256, 0, stream>>>(eo, sidx, eob);

    hipMemsetAsync(bar, 0, 256, stream);
    k_loop<<<NBLK, 256, 0, stream>>>(eo, eob, sidx, dlen, caps_s, emb,
                                     Wda, bda, Wfb, bfb, wfull, bfull,
                                     Wih, Whh, bih, bhh, att1,
                                     hseqR, cb0, cb1, fg, alphaW,
                                     xT, part, out, bar);
    k_predsall<<<dim3(TD, 16), 256, 0, stream>>>(hseqR, Wfc, bfc, dlen, out);
}